// Round 1
// baseline (1075.029 us; speedup 1.0000x reference)
//
#include <hip/hip_runtime.h>

#define TOKENS 8192
#define D_IN   4096
#define D_OUT  11008
#define BM 128
#define BN 128
#define BK 32
#define KSTEPS (D_IN / BK)

typedef __attribute__((ext_vector_type(8))) short bf16x8;
typedef __attribute__((ext_vector_type(4))) short bf16x4;
typedef __attribute__((ext_vector_type(4))) float f32x4;
typedef __attribute__((ext_vector_type(4))) int   i32x4;
typedef unsigned short u16;

__device__ __forceinline__ u16 to_bf16_rne(float f) {
  union { float f; unsigned u; } v; v.f = f;
  return (u16)((v.u + 0x7FFFu + ((v.u >> 16) & 1u)) >> 16);
}

// ---------- prepass: f32 -> bf16 (RNE) ----------
__global__ void cvt_x_kernel(const float* __restrict__ in, u16* __restrict__ out, long n4) {
  long i = (long)blockIdx.x * blockDim.x + threadIdx.x;
  const long stride = (long)gridDim.x * blockDim.x;
  for (; i < n4; i += stride) {
    f32x4 v = ((const f32x4*)in)[i];
    bf16x4 o;
    o.x = (short)to_bf16_rne(v[0]);
    o.y = (short)to_bf16_rne(v[1]);
    o.z = (short)to_bf16_rne(v[2]);
    o.w = (short)to_bf16_rne(v[3]);
    ((bf16x4*)out)[i] = o;
  }
}

// ---------- prepass: int32 (in [-127,127]) -> bf16 (exact) ----------
__global__ void cvt_w_kernel(const int* __restrict__ in, u16* __restrict__ out, long n4) {
  long i = (long)blockIdx.x * blockDim.x + threadIdx.x;
  const long stride = (long)gridDim.x * blockDim.x;
  for (; i < n4; i += stride) {
    i32x4 v = ((const i32x4*)in)[i];
    bf16x4 o;
    o.x = (short)to_bf16_rne((float)v[0]);
    o.y = (short)to_bf16_rne((float)v[1]);
    o.z = (short)to_bf16_rne((float)v[2]);
    o.w = (short)to_bf16_rne((float)v[3]);
    ((bf16x4*)out)[i] = o;
  }
}

__device__ __forceinline__ void gl_lds16(const u16* g, u16* l) {
  __builtin_amdgcn_global_load_lds(
      (const __attribute__((address_space(1))) void*)g,
      (__attribute__((address_space(3))) void*)l,
      16, 0, 0);
}

// ---------- path 1: bf16 GEMM (A [M][K], B [N][K], both bf16 in ws) ----------
// m97 structure: 128x128 tile, BK=32, 4 waves (2x2), each wave 64x64 = 4x4 frags
__global__ __launch_bounds__(256) void gemm_bf16(
    const u16* __restrict__ A, const u16* __restrict__ B,
    const float* __restrict__ scale, const float* __restrict__ bias,
    float* __restrict__ C) {
  __shared__ u16 lds_a[BM * BK];  // 8 KB, row-major [128][32], linear (gload_lds)
  __shared__ u16 lds_b[BM * BK];

  const int tid  = threadIdx.x;
  const int lane = tid & 63;
  const int wave = tid >> 6;
  const int wm = wave >> 1, wn = wave & 1;

  const long m0 = (long)blockIdx.y * BM;
  const long n0 = (long)blockIdx.x * BN;

  // staging: thread t covers tile bytes [t*16, t*16+16) (iter0) and +4096 (iter1)
  const int srow = tid >> 2;           // 0..63
  const int scol = (tid & 3) * 8;      // ushort offset within row

  const u16* gA0 = A + (m0 + srow) * (long)D_IN + scol;
  const u16* gA1 = gA0 + 64L * D_IN;
  const u16* gB0 = B + (n0 + srow) * (long)D_IN + scol;
  const u16* gB1 = gB0 + 64L * D_IN;

  // wave-uniform LDS bases (HW adds lane*16B)
  u16* la0 = lds_a + (wave * 64) * 8;
  u16* la1 = la0 + 256 * 8;
  u16* lb0 = lds_b + (wave * 64) * 8;
  u16* lb1 = lb0 + 256 * 8;

  f32x4 acc[4][4] = {};

  const int fr = lane & 15;
  const int fk = (lane >> 4) * 8;
  const u16* fa = lds_a + (wm * 64 + fr) * BK + fk;
  const u16* fb = lds_b + (wn * 64 + fr) * BK + fk;

  for (int kk = 0; kk < KSTEPS; ++kk) {
    const int ko = kk * BK;
    gl_lds16(gA0 + ko, la0);
    gl_lds16(gA1 + ko, la1);
    gl_lds16(gB0 + ko, lb0);
    gl_lds16(gB1 + ko, lb1);
    __syncthreads();  // drains vmcnt -> tiles resident

    bf16x8 af[4], bfr[4];
#pragma unroll
    for (int m = 0; m < 4; ++m) af[m] = *(const bf16x8*)(fa + m * 16 * BK);
#pragma unroll
    for (int n = 0; n < 4; ++n) bfr[n] = *(const bf16x8*)(fb + n * 16 * BK);
#pragma unroll
    for (int m = 0; m < 4; ++m)
#pragma unroll
      for (int n = 0; n < 4; ++n)
        acc[m][n] = __builtin_amdgcn_mfma_f32_16x16x32_bf16(af[m], bfr[n], acc[m][n], 0, 0, 0);
    __syncthreads();  // all reads done before next overwrite
  }

  // C/D layout: col = lane&15, row = (lane>>4)*4 + v  [m89/m91 verified]
  const int crow = (lane >> 4) * 4;
  const int ccol = lane & 15;
#pragma unroll
  for (int n = 0; n < 4; ++n) {
    const long col = n0 + wn * 64 + n * 16 + ccol;
    const float sc = scale[col];
    const float bz = bias[col];
#pragma unroll
    for (int m = 0; m < 4; ++m) {
      const long row = m0 + wm * 64 + m * 16 + crow;
      f32x4 a = acc[m][n];
#pragma unroll
      for (int v = 0; v < 4; ++v)
        C[(row + v) * (long)D_OUT + col] = a[v] * sc + bz;
    }
  }
}

// ---------- path 2 (fallback if ws too small): convert-in-kernel, reg staging ----------
__global__ __launch_bounds__(256) void gemm_cvt(
    const float* __restrict__ X, const int* __restrict__ W,
    const float* __restrict__ scale, const float* __restrict__ bias,
    float* __restrict__ C) {
  __shared__ u16 lds_a[BM * BK];
  __shared__ u16 lds_b[BM * BK];

  const int tid  = threadIdx.x;
  const int lane = tid & 63;
  const int wave = tid >> 6;
  const int wm = wave >> 1, wn = wave & 1;

  const long m0 = (long)blockIdx.y * BM;
  const long n0 = (long)blockIdx.x * BN;

  const int arow = tid >> 3;        // 0..31 (4 row-groups of 32)
  const int acol = (tid & 7) * 4;

  const float* gX = X + (m0 + arow) * (long)D_IN + acol;
  const int*   gW = W + (n0 + arow) * (long)D_IN + acol;

  u16* wla = lds_a + arow * BK + acol;
  u16* wlb = lds_b + arow * BK + acol;

  f32x4 acc[4][4] = {};
  const int fr = lane & 15;
  const int fk = (lane >> 4) * 8;
  const u16* fa = lds_a + (wm * 64 + fr) * BK + fk;
  const u16* fb = lds_b + (wn * 64 + fr) * BK + fk;

  for (int kk = 0; kk < KSTEPS; ++kk) {
    const long ko = (long)kk * BK;
    f32x4 xv[4]; i32x4 wv[4];
#pragma unroll
    for (int j = 0; j < 4; ++j) {
      xv[j] = *(const f32x4*)(gX + (long)j * 32 * D_IN + ko);
      wv[j] = *(const i32x4*)(gW + (long)j * 32 * D_IN + ko);
    }
    __syncthreads();  // previous compute finished reading LDS
#pragma unroll
    for (int j = 0; j < 4; ++j) {
      bf16x4 oa, ob;
      oa.x = (short)to_bf16_rne(xv[j][0]);
      oa.y = (short)to_bf16_rne(xv[j][1]);
      oa.z = (short)to_bf16_rne(xv[j][2]);
      oa.w = (short)to_bf16_rne(xv[j][3]);
      ob.x = (short)to_bf16_rne((float)wv[j][0]);
      ob.y = (short)to_bf16_rne((float)wv[j][1]);
      ob.z = (short)to_bf16_rne((float)wv[j][2]);
      ob.w = (short)to_bf16_rne((float)wv[j][3]);
      *(bf16x4*)(wla + j * 32 * BK) = oa;
      *(bf16x4*)(wlb + j * 32 * BK) = ob;
    }
    __syncthreads();

    bf16x8 af[4], bfr[4];
#pragma unroll
    for (int m = 0; m < 4; ++m) af[m] = *(const bf16x8*)(fa + m * 16 * BK);
#pragma unroll
    for (int n = 0; n < 4; ++n) bfr[n] = *(const bf16x8*)(fb + n * 16 * BK);
#pragma unroll
    for (int m = 0; m < 4; ++m)
#pragma unroll
      for (int n = 0; n < 4; ++n)
        acc[m][n] = __builtin_amdgcn_mfma_f32_16x16x32_bf16(af[m], bfr[n], acc[m][n], 0, 0, 0);
  }

  const int crow = (lane >> 4) * 4;
  const int ccol = lane & 15;
#pragma unroll
  for (int n = 0; n < 4; ++n) {
    const long col = n0 + wn * 64 + n * 16 + ccol;
    const float sc = scale[col];
    const float bz = bias[col];
#pragma unroll
    for (int m = 0; m < 4; ++m) {
      const long row = m0 + wm * 64 + m * 16 + crow;
      f32x4 a = acc[m][n];
#pragma unroll
      for (int v = 0; v < 4; ++v)
        C[(row + v) * (long)D_OUT + col] = a[v] * sc + bz;
    }
  }
}

extern "C" void kernel_launch(void* const* d_in, const int* in_sizes, int n_in,
                              void* d_out, int out_size, void* d_ws, size_t ws_size,
                              hipStream_t stream) {
  const float* x  = (const float*)d_in[0];
  const int*   wq = (const int*)d_in[1];
  const float* mx = (const float*)d_in[2];
  const float* bs = (const float*)d_in[3];
  float* out = (float*)d_out;

  const size_t needA = (size_t)TOKENS * D_IN * sizeof(u16);   // 67 MB
  const size_t needB = (size_t)D_OUT  * D_IN * sizeof(u16);   // 90 MB

  dim3 grid(D_OUT / BN, TOKENS / BM);  // 86 x 64
  if (ws_size >= needA + needB) {
    u16* xb = (u16*)d_ws;
    u16* wb = xb + (size_t)TOKENS * D_IN;
    cvt_x_kernel<<<2048, 256, 0, stream>>>(x, xb, (long)TOKENS * D_IN / 4);
    cvt_w_kernel<<<2048, 256, 0, stream>>>(wq, wb, (long)D_OUT * D_IN / 4);
    gemm_bf16<<<grid, 256, 0, stream>>>(xb, wb, mx, bs, out);
  } else {
    gemm_cvt<<<grid, 256, 0, stream>>>(x, wq, mx, bs, out);
  }
}

// Round 2
// 839.645 us; speedup vs baseline: 1.2803x; 1.2803x over previous
//
#include <hip/hip_runtime.h>

// W8Linear: y[t,o] = sum_k x[t,k] * (wq[o,k]*scale[o]) + bias[o]
// Strategy: wq (ints in [-127,127]) are EXACT in bf16; x->bf16 RNE loses 2^-9 rel.
// So: cvt prepass to bf16 in d_ws, then 256x256 8-wave MFMA GEMM with
// T1 (XCD swizzle) + T2 (LDS XOR swizzle) + T3/T4 (phased schedule, counted vmcnt)
// + T5 (setprio), using a 4-deep K-tile LDS ring (WAR-free by construction).
// scale/bias folded into the epilogue (per-output-col).

#define M_TOK 8192
#define K_DIM 4096
#define N_OUT 11008
#define BM 256
#define BN 256
#define BK 32
#define NT (K_DIM / BK)    // 128 K-tiles
#define NBM (M_TOK / BM)   // 32
#define NBN (N_OUT / BN)   // 43
#define NWG (NBM * NBN)    // 1376 = 8 * 172

typedef __attribute__((ext_vector_type(8))) short bf16x8;
typedef __attribute__((ext_vector_type(4))) short bf16x4;
typedef __attribute__((ext_vector_type(4))) float f32x4;
typedef __attribute__((ext_vector_type(4))) int   i32x4;
typedef unsigned short u16;

__device__ __forceinline__ u16 to_bf16_rne(float f) {
  union { float f; unsigned u; } v; v.f = f;
  return (u16)((v.u + 0x7FFFu + ((v.u >> 16) & 1u)) >> 16);
}

// ---------- prepass: f32 -> bf16 (RNE) ----------
__global__ void cvt_x_kernel(const float* __restrict__ in, u16* __restrict__ out, long n4) {
  long i = (long)blockIdx.x * blockDim.x + threadIdx.x;
  const long stride = (long)gridDim.x * blockDim.x;
  for (; i < n4; i += stride) {
    f32x4 v = ((const f32x4*)in)[i];
    bf16x4 o;
    o.x = (short)to_bf16_rne(v[0]);
    o.y = (short)to_bf16_rne(v[1]);
    o.z = (short)to_bf16_rne(v[2]);
    o.w = (short)to_bf16_rne(v[3]);
    ((bf16x4*)out)[i] = o;
  }
}

// ---------- prepass: int32 (in [-127,127]) -> bf16 (exact) ----------
__global__ void cvt_w_kernel(const int* __restrict__ in, u16* __restrict__ out, long n4) {
  long i = (long)blockIdx.x * blockDim.x + threadIdx.x;
  const long stride = (long)gridDim.x * blockDim.x;
  for (; i < n4; i += stride) {
    i32x4 v = ((const i32x4*)in)[i];
    bf16x4 o;
    o.x = (short)to_bf16_rne((float)v[0]);
    o.y = (short)to_bf16_rne((float)v[1]);
    o.z = (short)to_bf16_rne((float)v[2]);
    o.w = (short)to_bf16_rne((float)v[3]);
    ((bf16x4*)out)[i] = o;
  }
}

__device__ __forceinline__ void gl_lds16(const u16* g, u16* l) {
  __builtin_amdgcn_global_load_lds(
      (const __attribute__((address_space(1))) void*)g,
      (__attribute__((address_space(3))) void*)l,
      16, 0, 0);
}

// ===================== 256x256 phased GEMM =====================
// 8 waves (2M x 4N); per-wave 128x64 output = acc[8][4] f32x4.
// LDS: 4-slot ring, slot = A[256][32] + B[256][32] bf16 = 32KB -> 128KB total.
// T2 swizzle (involution, 16B granular): byte ^= ((byte>>7)&3)<<4
//   (bank-slot bits 4-5 XOR row bits 1-2; frag-read 16 rows hit all 8 slots, 2-way = free)
// Schedule per K-tile (2 phases, 16 MFMA each):
//   phA: ds_read A-frags 0-3 + B-frags 0-3 | stage A-chunks(t+2) | bar | lgkm0 | prio1 16xMFMA prio0 | bar
//   phB: ds_read A-frags 4-7               | stage B-chunks(t+2) | bar | lgkm0 | prio1 16xMFMA prio0 | vmcnt(4) bar
// Ledger: entering tile t: 4 outstanding (= tile t+1 chunks). +4 during t, vmcnt(4)
// at boundary -> tile t+1 fully landed, tile t+2 in flight. Never 0 in main loop.
__global__ __launch_bounds__(512, 2) void gemm256(
    const u16* __restrict__ A, const u16* __restrict__ B,
    const float* __restrict__ scale, const float* __restrict__ bias,
    float* __restrict__ C) {
  __shared__ u16 lds[65536];  // 128 KiB

  const int tid  = threadIdx.x;
  const int lane = tid & 63;
  const int wave = tid >> 6;
  const int wm = wave >> 2;  // 0..1
  const int wn = wave & 3;   // 0..3

  // T1: XCD-aware bijective swizzle (NWG % 8 == 0)
  const int swz = (blockIdx.x & 7) * (NWG / 8) + (blockIdx.x >> 3);
  const int bm = swz / NBN;
  const int bn = swz % NBN;
  const long m0 = (long)bm * BM;
  const long n0 = (long)bn * BN;

  // ---- staging source (pre-swizzled global; rule #21) ----
  // linear LDS byte L = chunk*8192 + wave*1024 + lane*16 ; r = L>>6 = tid>>2 (+128 for chunk1)
  // logical col(u16) = (tid&3)*8 ^ ((r>>1)&3)<<3   (chunk1: +128 rows keeps (r>>1)&3)
  const int rs = tid >> 2;  // 0..127
  const int cs = ((tid & 3) * 8) ^ (((rs >> 1) & 3) << 3);
  const u16* pA0 = A + (m0 + rs) * (long)K_DIM + cs;
  const u16* pA1 = pA0 + 128L * K_DIM;
  const u16* pB0 = B + (n0 + rs) * (long)K_DIM + cs;
  const u16* pB1 = pB0 + 128L * K_DIM;
  const int dwa = wave * 512;  // u16: wave's 1KB segment within an 8KB chunk

  // ---- fragment read offsets (bytes, swizzled) ----
  const int inner = ((lane >> 4) * 16) ^ ((((lane & 15) >> 1) & 3) << 4);
  const int abase = (wm * 128 + (lane & 15)) * 64 + inner;           // A region
  const int bbase = 16384 + (wn * 64 + (lane & 15)) * 64 + inner;    // B region
  const char* ldsc = (const char*)lds;

  f32x4 acc[8][4] = {};

  // ---- prologue: stage tiles 0,1 into slots 0,1; drain once ----
  gl_lds16(pA0 + 0, lds + 0 + dwa);
  gl_lds16(pA1 + 0, lds + 4096 + dwa);
  gl_lds16(pB0 + 0, lds + 8192 + dwa);
  gl_lds16(pB1 + 0, lds + 12288 + dwa);
  gl_lds16(pA0 + BK, lds + 16384 + dwa);
  gl_lds16(pA1 + BK, lds + 16384 + 4096 + dwa);
  gl_lds16(pB0 + BK, lds + 16384 + 8192 + dwa);
  gl_lds16(pB1 + BK, lds + 16384 + 12288 + dwa);
  asm volatile("s_waitcnt vmcnt(0)" ::: "memory");
  __builtin_amdgcn_sched_barrier(0);
  __builtin_amdgcn_s_barrier();

  int koff = 2 * BK;  // k (u16) of tile t+2
  for (int t = 0; t < NT; ++t) {
    const int rb = (t & 3) * 32768;            // read slot, bytes
    const int ws = ((t + 2) & 3) * 16384;      // write slot, u16
    const bool st = (t < NT - 2);
    const char* pa = ldsc + rb + abase;
    const char* pb = ldsc + rb + bbase;

    // ---------- phase A ----------
    bf16x8 af[4], bfv[4];
#pragma unroll
    for (int m = 0; m < 4; ++m) af[m] = *(const bf16x8*)(pa + m * 1024);
#pragma unroll
    for (int n = 0; n < 4; ++n) bfv[n] = *(const bf16x8*)(pb + n * 1024);
    if (st) {
      gl_lds16(pA0 + koff, lds + ws + dwa);
      gl_lds16(pA1 + koff, lds + ws + 4096 + dwa);
    }
    __builtin_amdgcn_s_barrier();
    asm volatile("s_waitcnt lgkmcnt(0)" ::: "memory");
    __builtin_amdgcn_sched_barrier(0);
    __builtin_amdgcn_s_setprio(1);
#pragma unroll
    for (int m = 0; m < 4; ++m)
#pragma unroll
      for (int n = 0; n < 4; ++n)
        acc[m][n] = __builtin_amdgcn_mfma_f32_16x16x32_bf16(af[m], bfv[n], acc[m][n], 0, 0, 0);
    __builtin_amdgcn_s_setprio(0);
    __builtin_amdgcn_s_barrier();

    // ---------- phase B ----------
    bf16x8 ag[4];
#pragma unroll
    for (int m = 0; m < 4; ++m) ag[m] = *(const bf16x8*)(pa + (m + 4) * 1024);
    if (st) {
      gl_lds16(pB0 + koff, lds + ws + 8192 + dwa);
      gl_lds16(pB1 + koff, lds + ws + 12288 + dwa);
    }
    __builtin_amdgcn_s_barrier();
    asm volatile("s_waitcnt lgkmcnt(0)" ::: "memory");
    __builtin_amdgcn_sched_barrier(0);
    __builtin_amdgcn_s_setprio(1);
#pragma unroll
    for (int m = 0; m < 4; ++m)
#pragma unroll
      for (int n = 0; n < 4; ++n)
        acc[m + 4][n] = __builtin_amdgcn_mfma_f32_16x16x32_bf16(ag[m], bfv[n], acc[m + 4][n], 0, 0, 0);
    __builtin_amdgcn_s_setprio(0);
    // tile boundary: counted wait (T4); tail tiles drain
    if (st) { asm volatile("s_waitcnt vmcnt(4)" ::: "memory"); }
    else    { asm volatile("s_waitcnt vmcnt(0)" ::: "memory"); }
    __builtin_amdgcn_sched_barrier(0);
    __builtin_amdgcn_s_barrier();
    koff += BK;
  }

  // ---- epilogue: scale/bias, f32 store ----
  // C/D layout: col = lane&15, row = (lane>>4)*4 + v   [m89/m91]
  const int crow = (lane >> 4) * 4;
  const int ccol = lane & 15;
#pragma unroll
  for (int n = 0; n < 4; ++n) {
    const long col = n0 + wn * 64 + n * 16 + ccol;
    const float sc = scale[col];
    const float bz = bias[col];
#pragma unroll
    for (int m = 0; m < 8; ++m) {
      const long row = m0 + wm * 128 + m * 16 + crow;
      f32x4 a = acc[m][n];
#pragma unroll
      for (int v = 0; v < 4; ++v)
        C[(row + v) * (long)N_OUT + col] = a[v] * sc + bz;
    }
  }
}

// ---------- fallback (ws too small): 128^2 convert-in-kernel ----------
__global__ __launch_bounds__(256) void gemm_cvt(
    const float* __restrict__ X, const int* __restrict__ W,
    const float* __restrict__ scale, const float* __restrict__ bias,
    float* __restrict__ C) {
  __shared__ u16 lds_a[128 * 32];
  __shared__ u16 lds_b[128 * 32];

  const int tid  = threadIdx.x;
  const int lane = tid & 63;
  const int wave = tid >> 6;
  const int wm = wave >> 1, wn = wave & 1;

  const long m0 = (long)blockIdx.y * 128;
  const long n0 = (long)blockIdx.x * 128;

  const int arow = tid >> 3;
  const int acol = (tid & 7) * 4;

  const float* gX = X + (m0 + arow) * (long)K_DIM + acol;
  const int*   gW = W + (n0 + arow) * (long)K_DIM + acol;

  u16* wla = lds_a + arow * 32 + acol;
  u16* wlb = lds_b + arow * 32 + acol;

  f32x4 acc[4][4] = {};
  const int fr = lane & 15;
  const int fk = (lane >> 4) * 8;
  const u16* fa = lds_a + (wm * 64 + fr) * 32 + fk;
  const u16* fb = lds_b + (wn * 64 + fr) * 32 + fk;

  for (int kk = 0; kk < K_DIM / 32; ++kk) {
    const long ko = (long)kk * 32;
    f32x4 xv[4]; i32x4 wv[4];
#pragma unroll
    for (int j = 0; j < 4; ++j) {
      xv[j] = *(const f32x4*)(gX + (long)j * 32 * K_DIM + ko);
      wv[j] = *(const i32x4*)(gW + (long)j * 32 * K_DIM + ko);
    }
    __syncthreads();
#pragma unroll
    for (int j = 0; j < 4; ++j) {
      bf16x4 oa, ob;
      oa.x = (short)to_bf16_rne(xv[j][0]);
      oa.y = (short)to_bf16_rne(xv[j][1]);
      oa.z = (short)to_bf16_rne(xv[j][2]);
      oa.w = (short)to_bf16_rne(xv[j][3]);
      ob.x = (short)to_bf16_rne((float)wv[j][0]);
      ob.y = (short)to_bf16_rne((float)wv[j][1]);
      ob.z = (short)to_bf16_rne((float)wv[j][2]);
      ob.w = (short)to_bf16_rne((float)wv[j][3]);
      *(bf16x4*)(wla + j * 32 * 32) = oa;
      *(bf16x4*)(wlb + j * 32 * 32) = ob;
    }
    __syncthreads();

    bf16x8 af[4], bfr[4];
#pragma unroll
    for (int m = 0; m < 4; ++m) af[m] = *(const bf16x8*)(fa + m * 16 * 32);
#pragma unroll
    for (int n = 0; n < 4; ++n) bfr[n] = *(const bf16x8*)(fb + n * 16 * 32);
#pragma unroll
    for (int m = 0; m < 4; ++m)
#pragma unroll
      for (int n = 0; n < 4; ++n)
        acc[m][n] = __builtin_amdgcn_mfma_f32_16x16x32_bf16(af[m], bfr[n], acc[m][n], 0, 0, 0);
  }

  const int crow = (lane >> 4) * 4;
  const int ccol = lane & 15;
#pragma unroll
  for (int n = 0; n < 4; ++n) {
    const long col = n0 + wn * 64 + n * 16 + ccol;
    const float sc = scale[col];
    const float bz = bias[col];
#pragma unroll
    for (int m = 0; m < 4; ++m) {
      const long row = m0 + wm * 64 + m * 16 + crow;
      f32x4 a = acc[m][n];
#pragma unroll
      for (int v = 0; v < 4; ++v)
        C[(row + v) * (long)N_OUT + col] = a[v] * sc + bz;
    }
  }
}

extern "C" void kernel_launch(void* const* d_in, const int* in_sizes, int n_in,
                              void* d_out, int out_size, void* d_ws, size_t ws_size,
                              hipStream_t stream) {
  const float* x  = (const float*)d_in[0];
  const int*   wq = (const int*)d_in[1];
  const float* mx = (const float*)d_in[2];
  const float* bs = (const float*)d_in[3];
  float* out = (float*)d_out;

  const size_t needA = (size_t)M_TOK * K_DIM * sizeof(u16);
  const size_t needB = (size_t)N_OUT * K_DIM * sizeof(u16);

  if (ws_size >= needA + needB) {
    u16* xb = (u16*)d_ws;
    u16* wb = xb + (size_t)M_TOK * K_DIM;
    cvt_x_kernel<<<2048, 256, 0, stream>>>(x, xb, (long)M_TOK * K_DIM / 4);
    cvt_w_kernel<<<2048, 256, 0, stream>>>(wq, wb, (long)N_OUT * K_DIM / 4);
    gemm256<<<dim3(NWG), dim3(512), 0, stream>>>(xb, wb, mx, bs, out);
  } else {
    dim3 grid(N_OUT / 128, M_TOK / 128);
    gemm_cvt<<<grid, 256, 0, stream>>>(x, wq, mx, bs, out);
  }
}

// Round 3
// 791.520 us; speedup vs baseline: 1.3582x; 1.0608x over previous
//
#include <hip/hip_runtime.h>

// W8Linear: y[t,o] = sum_k x[t,k] * (wq[o,k]*scale[o]) + bias[o]
// wq in [-127,127] is EXACT in bf16; x->bf16 RNE. cvt prepass -> bf16 GEMM.
// R3: 256x256 tile, BK=32, 8 waves, ring-4 LDS, stage-ahead-3, ONE barrier
// per K-tile, counted vmcnt(4), per-wave software-pipelined frag reads
// (read-ahead t+1 between MFMA clusters), compiler-managed counted lgkm,
// setprio around MFMA clusters, T1 XCD swizzle + T2 LDS XOR swizzle.

#define M_TOK 8192
#define K_DIM 4096
#define N_OUT 11008
#define BM 256
#define BN 256
#define BK 32
#define NT (K_DIM / BK)    // 128 K-tiles
#define NBM (M_TOK / BM)   // 32
#define NBN (N_OUT / BN)   // 43
#define NWG (NBM * NBN)    // 1376 = 8 * 172

typedef __attribute__((ext_vector_type(8))) short bf16x8;
typedef __attribute__((ext_vector_type(4))) short bf16x4;
typedef __attribute__((ext_vector_type(4))) float f32x4;
typedef __attribute__((ext_vector_type(4))) int   i32x4;
typedef unsigned short u16;

__device__ __forceinline__ u16 to_bf16_rne(float f) {
  union { float f; unsigned u; } v; v.f = f;
  return (u16)((v.u + 0x7FFFu + ((v.u >> 16) & 1u)) >> 16);
}

__global__ void cvt_x_kernel(const float* __restrict__ in, u16* __restrict__ out, long n4) {
  long i = (long)blockIdx.x * blockDim.x + threadIdx.x;
  const long stride = (long)gridDim.x * blockDim.x;
  for (; i < n4; i += stride) {
    f32x4 v = ((const f32x4*)in)[i];
    bf16x4 o;
    o.x = (short)to_bf16_rne(v[0]);
    o.y = (short)to_bf16_rne(v[1]);
    o.z = (short)to_bf16_rne(v[2]);
    o.w = (short)to_bf16_rne(v[3]);
    ((bf16x4*)out)[i] = o;
  }
}

__global__ void cvt_w_kernel(const int* __restrict__ in, u16* __restrict__ out, long n4) {
  long i = (long)blockIdx.x * blockDim.x + threadIdx.x;
  const long stride = (long)gridDim.x * blockDim.x;
  for (; i < n4; i += stride) {
    i32x4 v = ((const i32x4*)in)[i];
    bf16x4 o;
    o.x = (short)to_bf16_rne((float)v[0]);
    o.y = (short)to_bf16_rne((float)v[1]);
    o.z = (short)to_bf16_rne((float)v[2]);
    o.w = (short)to_bf16_rne((float)v[3]);
    ((bf16x4*)out)[i] = o;
  }
}

__device__ __forceinline__ void gl_lds16(const u16* g, u16* l) {
  __builtin_amdgcn_global_load_lds(
      (const __attribute__((address_space(1))) void*)g,
      (__attribute__((address_space(3))) void*)l,
      16, 0, 0);
}

// stage all 4 chunks (A0,A1,B0,B1) of K-tile T into ring slot T&3
#define STAGE(T) do { \
    u16* wsl = lds + ((T) & 3) * 16384; \
    const int ko = (T) * BK; \
    gl_lds16(pA0 + ko, wsl + dwa); \
    gl_lds16(pA1 + ko, wsl + 4096 + dwa); \
    gl_lds16(pB0 + ko, wsl + 8192 + dwa); \
    gl_lds16(pB1 + ko, wsl + 12288 + dwa); \
  } while (0)

// One K-tile: AFC/BVC = current frag regs, AFN/BVN = next-tile regs, RA = do read-ahead
#define TILE_BODY(T, AFC, BVC, AFN, BVN, RA) do { \
    const char* pa_ = ldsc + ((T) & 3) * 32768 + abase; \
    _Pragma("unroll") \
    for (int m = 0; m < 4; ++m) ag[m] = *(const bf16x8*)(pa_ + (m + 4) * 1024); \
    if ((T) <= NT - 4) STAGE((T) + 3); \
    __builtin_amdgcn_s_setprio(1); \
    _Pragma("unroll") \
    for (int m = 0; m < 4; ++m) \
      _Pragma("unroll") \
      for (int n = 0; n < 4; ++n) \
        acc[m][n] = __builtin_amdgcn_mfma_f32_16x16x32_bf16(AFC[m], BVC[n], acc[m][n], 0, 0, 0); \
    __builtin_amdgcn_s_setprio(0); \
    if (RA) { \
      const char* qa_ = ldsc + (((T) + 1) & 3) * 32768 + abase; \
      const char* qb_ = ldsc + (((T) + 1) & 3) * 32768 + bbase; \
      _Pragma("unroll") \
      for (int m = 0; m < 4; ++m) AFN[m] = *(const bf16x8*)(qa_ + m * 1024); \
      _Pragma("unroll") \
      for (int n = 0; n < 4; ++n) BVN[n] = *(const bf16x8*)(qb_ + n * 1024); \
    } \
    __builtin_amdgcn_s_setprio(1); \
    _Pragma("unroll") \
    for (int m = 0; m < 4; ++m) \
      _Pragma("unroll") \
      for (int n = 0; n < 4; ++n) \
        acc[m + 4][n] = __builtin_amdgcn_mfma_f32_16x16x32_bf16(ag[m], BVC[n], acc[m + 4][n], 0, 0, 0); \
    __builtin_amdgcn_s_setprio(0); \
    if ((T) <= NT - 4) { asm volatile("s_waitcnt vmcnt(4)" ::: "memory"); } \
    else               { asm volatile("s_waitcnt vmcnt(0)" ::: "memory"); } \
    __builtin_amdgcn_sched_barrier(0); \
    __builtin_amdgcn_s_barrier(); \
  } while (0)

__global__ __launch_bounds__(512, 2) void gemm256(
    const u16* __restrict__ A, const u16* __restrict__ B,
    const float* __restrict__ scale, const float* __restrict__ bias,
    float* __restrict__ C) {
  __shared__ u16 lds[65536];  // 128 KiB: 4 ring slots x (A 16KB + B 16KB)

  const int tid  = threadIdx.x;
  const int lane = tid & 63;
  const int wave = tid >> 6;
  const int wm = wave >> 2;  // 0..1
  const int wn = wave & 3;   // 0..3

  // T1: XCD-aware bijective swizzle (NWG % 8 == 0)
  const int swz = (blockIdx.x & 7) * (NWG / 8) + (blockIdx.x >> 3);
  const int bm = swz / NBN;
  const int bn = swz % NBN;
  const long m0 = (long)bm * BM;
  const long n0 = (long)bn * BN;

  // ---- staging source (pre-swizzled global; rule #21) ----
  const int rs = tid >> 2;  // 0..127 (row within 128-row chunk)
  const int cs = ((tid & 3) * 8) ^ (((rs >> 1) & 3) << 3);
  const u16* pA0 = A + (m0 + rs) * (long)K_DIM + cs;
  const u16* pA1 = pA0 + 128L * K_DIM;
  const u16* pB0 = B + (n0 + rs) * (long)K_DIM + cs;
  const u16* pB1 = pB0 + 128L * K_DIM;
  const int dwa = wave * 512;  // u16: wave's 1KB segment within an 8KB chunk

  // ---- fragment read offsets (bytes, T2-swizzled) ----
  const int inner = ((lane >> 4) * 16) ^ ((((lane & 15) >> 1) & 3) << 4);
  const int abase = (wm * 128 + (lane & 15)) * 64 + inner;           // A region
  const int bbase = 16384 + (wn * 64 + (lane & 15)) * 64 + inner;    // B region
  const char* ldsc = (const char*)lds;

  f32x4 acc[8][4] = {};
  bf16x8 afE[4], bvE[4], afO[4], bvO[4], ag[4];

  // ---- prologue: stage tiles 0,1,2; wait tiles 0,1 landed; preload frags(0) ----
  STAGE(0); STAGE(1); STAGE(2);
  asm volatile("s_waitcnt vmcnt(4)" ::: "memory");
  __builtin_amdgcn_sched_barrier(0);
  __builtin_amdgcn_s_barrier();
  {
    const char* qa = ldsc + abase;
    const char* qb = ldsc + bbase;
#pragma unroll
    for (int m = 0; m < 4; ++m) afE[m] = *(const bf16x8*)(qa + m * 1024);
#pragma unroll
    for (int n = 0; n < 4; ++n) bvE[n] = *(const bf16x8*)(qb + n * 1024);
  }

  for (int t = 0; t < NT - 2; t += 2) {
    TILE_BODY(t,     afE, bvE, afO, bvO, 1);
    TILE_BODY(t + 1, afO, bvO, afE, bvE, 1);
  }
  TILE_BODY(NT - 2, afE, bvE, afO, bvO, 1);
  TILE_BODY(NT - 1, afO, bvO, afE, bvE, 0);

  // ---- epilogue: scale/bias, f32 store ----
  // C/D layout: col = lane&15, row = (lane>>4)*4 + v   [m89/m91]
  const int crow = (lane >> 4) * 4;
  const int ccol = lane & 15;
#pragma unroll
  for (int n = 0; n < 4; ++n) {
    const long col = n0 + wn * 64 + n * 16 + ccol;
    const float sc = scale[col];
    const float bz = bias[col];
#pragma unroll
    for (int m = 0; m < 8; ++m) {
      const long row = m0 + wm * 128 + m * 16 + crow;
      f32x4 a = acc[m][n];
#pragma unroll
      for (int v = 0; v < 4; ++v)
        C[(row + v) * (long)N_OUT + col] = a[v] * sc + bz;
    }
  }
}

// ---------- fallback (ws too small): 128^2 convert-in-kernel ----------
__global__ __launch_bounds__(256) void gemm_cvt(
    const float* __restrict__ X, const int* __restrict__ W,
    const float* __restrict__ scale, const float* __restrict__ bias,
    float* __restrict__ C) {
  __shared__ u16 lds_a[128 * 32];
  __shared__ u16 lds_b[128 * 32];

  const int tid  = threadIdx.x;
  const int lane = tid & 63;
  const int wave = tid >> 6;
  const int wm = wave >> 1, wn = wave & 1;

  const long m0 = (long)blockIdx.y * 128;
  const long n0 = (long)blockIdx.x * 128;

  const int arow = tid >> 3;
  const int acol = (tid & 7) * 4;

  const float* gX = X + (m0 + arow) * (long)K_DIM + acol;
  const int*   gW = W + (n0 + arow) * (long)K_DIM + acol;

  u16* wla = lds_a + arow * 32 + acol;
  u16* wlb = lds_b + arow * 32 + acol;

  f32x4 acc[4][4] = {};
  const int fr = lane & 15;
  const int fk = (lane >> 4) * 8;
  const u16* fa = lds_a + (wm * 64 + fr) * 32 + fk;
  const u16* fb = lds_b + (wn * 64 + fr) * 32 + fk;

  for (int kk = 0; kk < K_DIM / 32; ++kk) {
    const long ko = (long)kk * 32;
    f32x4 xv[4]; i32x4 wv[4];
#pragma unroll
    for (int j = 0; j < 4; ++j) {
      xv[j] = *(const f32x4*)(gX + (long)j * 32 * K_DIM + ko);
      wv[j] = *(const i32x4*)(gW + (long)j * 32 * K_DIM + ko);
    }
    __syncthreads();
#pragma unroll
    for (int j = 0; j < 4; ++j) {
      bf16x4 oa, ob;
      oa.x = (short)to_bf16_rne(xv[j][0]);
      oa.y = (short)to_bf16_rne(xv[j][1]);
      oa.z = (short)to_bf16_rne(xv[j][2]);
      oa.w = (short)to_bf16_rne(xv[j][3]);
      ob.x = (short)to_bf16_rne((float)wv[j][0]);
      ob.y = (short)to_bf16_rne((float)wv[j][1]);
      ob.z = (short)to_bf16_rne((float)wv[j][2]);
      ob.w = (short)to_bf16_rne((float)wv[j][3]);
      *(bf16x4*)(wla + j * 32 * 32) = oa;
      *(bf16x4*)(wlb + j * 32 * 32) = ob;
    }
    __syncthreads();

    bf16x8 af[4], bfr[4];
#pragma unroll
    for (int m = 0; m < 4; ++m) af[m] = *(const bf16x8*)(fa + m * 16 * 32);
#pragma unroll
    for (int n = 0; n < 4; ++n) bfr[n] = *(const bf16x8*)(fb + n * 16 * 32);
#pragma unroll
    for (int m = 0; m < 4; ++m)
#pragma unroll
      for (int n = 0; n < 4; ++n)
        acc[m][n] = __builtin_amdgcn_mfma_f32_16x16x32_bf16(af[m], bfr[n], acc[m][n], 0, 0, 0);
  }

  const int crow = (lane >> 4) * 4;
  const int ccol = lane & 15;
#pragma unroll
  for (int n = 0; n < 4; ++n) {
    const long col = n0 + wn * 64 + n * 16 + ccol;
    const float sc = scale[col];
    const float bz = bias[col];
#pragma unroll
    for (int m = 0; m < 4; ++m) {
      const long row = m0 + wm * 64 + m * 16 + crow;
      f32x4 a = acc[m][n];
#pragma unroll
      for (int v = 0; v < 4; ++v)
        C[(row + v) * (long)N_OUT + col] = a[v] * sc + bz;
    }
  }
}

extern "C" void kernel_launch(void* const* d_in, const int* in_sizes, int n_in,
                              void* d_out, int out_size, void* d_ws, size_t ws_size,
                              hipStream_t stream) {
  const float* x  = (const float*)d_in[0];
  const int*   wq = (const int*)d_in[1];
  const float* mx = (const float*)d_in[2];
  const float* bs = (const float*)d_in[3];
  float* out = (float*)d_out;

  const size_t needA = (size_t)M_TOK * K_DIM * sizeof(u16);
  const size_t needB = (size_t)N_OUT * K_DIM * sizeof(u16);

  if (ws_size >= needA + needB) {
    u16* xb = (u16*)d_ws;
    u16* wb = xb + (size_t)M_TOK * K_DIM;
    cvt_x_kernel<<<2048, 256, 0, stream>>>(x, xb, (long)M_TOK * K_DIM / 4);
    cvt_w_kernel<<<2048, 256, 0, stream>>>(wq, wb, (long)N_OUT * K_DIM / 4);
    gemm256<<<dim3(NWG), dim3(512), 0, stream>>>(xb, wb, mx, bs, out);
  } else {
    dim3 grid(N_OUT / 128, M_TOK / 128);
    gemm_cvt<<<grid, 256, 0, stream>>>(x, wq, mx, bs, out);
  }
}